// Round 11
// baseline (198.702 us; speedup 1.0000x reference)
//
#include <hip/hip_runtime.h>
#include <stdint.h>

#define BSz 4096   // B*S tokens
#define Ddim 1024
#define Fdim 4096
#define Edim 4
#define Rdim 4

typedef __attribute__((ext_vector_type(8))) short bf16x8;
typedef __attribute__((ext_vector_type(16))) float f32x16;

__device__ __forceinline__ unsigned short f2bf(float f) {
  union { float f; uint32_t u; } c; c.f = f;
  return (unsigned short)((c.u + 0x7fffu + ((c.u >> 16) & 1u)) >> 16);
}

// ---------------- fp32 -> bf16 conversion, 3 tensors in one launch ----------
__global__ __launch_bounds__(256) void cvt3_kernel(const float* __restrict__ x,
                                                   const float* __restrict__ wi,
                                                   const float* __restrict__ wo,
                                                   unsigned short* __restrict__ xb,
                                                   unsigned short* __restrict__ wib,
                                                   unsigned short* __restrict__ wob,
                                                   int n4) {
  int i = blockIdx.x * 256 + threadIdx.x;
  if (i >= n4) return;
  const float* src = (blockIdx.y == 0) ? x : (blockIdx.y == 1) ? wi : wo;
  unsigned short* dst = (blockIdx.y == 0) ? xb : (blockIdx.y == 1) ? wib : wob;
  float4 v = ((const float4*)src)[i];
  ushort4 o;
  o.x = f2bf(v.x); o.y = f2bf(v.y); o.z = f2bf(v.z); o.w = f2bf(v.w);
  ((ushort4*)dst)[i] = o;
}

// ---------------- router: logits -> softmax -> top2 + lora_low ----------------
__global__ __launch_bounds__(256) void router_kernel(const float* __restrict__ x,
                                                     const float* __restrict__ Wg,
                                                     const float* __restrict__ bg,
                                                     const float* __restrict__ Aw,
                                                     float* __restrict__ meta) {
  __shared__ float xs[Ddim];
  __shared__ float dots[Edim + Edim * Rdim];
  const int t = blockIdx.x;
  const float4* xt = (const float4*)(x + (size_t)t * Ddim);
  for (int i = threadIdx.x; i < Ddim / 4; i += 256) ((float4*)xs)[i] = xt[i];
  __syncthreads();
  const int wave = threadIdx.x >> 6, lane = threadIdx.x & 63;
  for (int d = wave * 5; d < wave * 5 + 5; ++d) {
    const float* wrow = (d < Edim) ? (Wg + (size_t)d * Ddim)
                                   : (Aw + (size_t)(d - Edim) * Ddim);
    float s = 0.f;
    for (int i = lane; i < Ddim; i += 64) s += xs[i] * wrow[i];
    for (int off = 32; off; off >>= 1) s += __shfl_down(s, off);
    if (lane == 0) dots[d] = s;
  }
  __syncthreads();
  if (threadIdx.x == 0) {
    float p[Edim];
    float m = -1e30f;
    for (int e = 0; e < Edim; ++e) { p[e] = dots[e] + bg[e]; m = fmaxf(m, p[e]); }
    float sum = 0.f;
    for (int e = 0; e < Edim; ++e) { p[e] = expf(p[e] - m); sum += p[e]; }
    const float inv = 1.f / sum;
    for (int e = 0; e < Edim; ++e) p[e] *= inv;
    int e0 = 0;
    for (int e = 1; e < Edim; ++e) if (p[e] > p[e0]) e0 = e;
    int e1 = (e0 == 0) ? 1 : 0;
    for (int e = 0; e < Edim; ++e) if (e != e0 && p[e] > p[e1]) e1 = e;
    float* mt = meta + (size_t)t * 16;
    mt[0] = (float)e0; mt[1] = (float)e1; mt[2] = p[e0]; mt[3] = p[e1];
    for (int r = 0; r < Rdim; ++r) {
      mt[4 + r] = dots[Edim + e0 * Rdim + r];
      mt[8 + r] = dots[Edim + e1 * Rdim + r];
    }
    mt[12] = 0.f; mt[13] = 0.f; mt[14] = 0.f; mt[15] = 0.f;
  }
}

// ---------------- m97-structure NT bf16 GEMM, 32x32x16 MFMA ----------------
// C[M,N] = A[M,K] rows bm.. * B[N,K]^T rows bn.. over K-slice [kbase,+kslice).
// 128x128 tile, BK=64, 4 waves (2x2), each wave 64x64 = 2x2 MFMA-tiles of
// 32x32. Single-buffered 32KB LDS, plain __syncthreads, 4 blocks/CU.
// 32x32x16 runs at 2495 TF ubench vs 2075 for 16x16x32 (+20% pipe eff).
// XOR chunk swizzle (chunk ^ row&7) via pre-swizzled source + swizzled read
// (R6-validated: 0 conflicts, faster than linear).
// A/B frag: row = lane&31, k = (lane>>5)*8 .. +7 (16B contiguous).
// C/D frag: col = lane&31, row = (reg&3) + 8*(reg>>2) + 4*(lane>>5).
// EPI==0: fused MoE epilogue -> outg bf16; also zeroes zbuf (split-K base).
// EPI==1: f32 atomicAdd into outf (split-K).
template <int EPI>
__global__ __launch_bounds__(256, 4)
void gemm32(const unsigned short* __restrict__ Ag,
            const unsigned short* __restrict__ Bg,
            int K, int kslice, int Ncols,
            const float* __restrict__ meta,
            const float* __restrict__ B2,
            unsigned short* __restrict__ outg,
            float* __restrict__ outf,
            float* __restrict__ zbuf) {
  constexpr int BK = 64;
  __shared__ __align__(16) unsigned short sA[128 * BK];   // 16 KB
  __shared__ __align__(16) unsigned short sB[128 * BK];   // 16 KB

  const int tid = threadIdx.x;
  const int lane = tid & 63;
  const int wave = tid >> 6;            // 0..3
  const int wr = wave >> 1, wc = wave & 1;
  const int l31 = lane & 31, lk = lane >> 5;

  // XCD-aware bijective swizzle on the xy grid (nwg per z-slice % 8 == 0)
  const int nwg = gridDim.x * gridDim.y;
  const int lin = blockIdx.y * gridDim.x + blockIdx.x;
  const int cpx = nwg >> 3;
  const int swz = (lin & 7) * cpx + (lin >> 3);
  const int bx = swz % gridDim.x, by = swz / gridDim.x;
  const int bm = by * 128, bn = bx * 128;
  const int kbase = blockIdx.z * kslice;
  const int NT = kslice / BK;

  // fused zero of the split-K accumulation target (GEMM1 only): 1024 blocks
  // x 256 thr x 4 float4 = 16 MB. Kernel boundary orders it before GEMM2.
  if (EPI == 0) {
    const float4 z4 = make_float4(0.f, 0.f, 0.f, 0.f);
#pragma unroll
    for (int zz = 0; zz < 4; ++zz)
      ((float4*)zbuf)[(size_t)lin * 1024 + zz * 256 + tid] = z4;
  }

  f32x16 acc[2][2] = {};

  // staging: LDS dest linear (tid*8 elems); source chunk pre-swizzled by the
  // involution chunk' = chunk ^ (row&7); round rr covers rows tid/8 + rr*32.
  const int srow = tid >> 3;                                  // 0..31
  const int scol = ((tid & 7) ^ (srow & 7)) * 8;              // swizzled col
  const int ldst = tid * 8;

  for (int kt = 0; kt < NT; ++kt) {
    const int kof = kbase + kt * BK;
#pragma unroll
    for (int rr = 0; rr < 4; ++rr)
      __builtin_amdgcn_global_load_lds(
          (const __attribute__((address_space(1))) void*)(Ag + (size_t)(bm + srow + rr * 32) * K + kof + scol),
          (__attribute__((address_space(3))) void*)(sA + ldst + rr * 2048), 16, 0, 0);
#pragma unroll
    for (int rr = 0; rr < 4; ++rr)
      __builtin_amdgcn_global_load_lds(
          (const __attribute__((address_space(1))) void*)(Bg + (size_t)(bn + srow + rr * 32) * K + kof + scol),
          (__attribute__((address_space(3))) void*)(sB + ldst + rr * 2048), 16, 0, 0);
    __syncthreads();
#pragma unroll
    for (int ks = 0; ks < 4; ++ks) {                  // 4 k-steps of 16
      const int ch = ks * 2 + lk;                     // 16B chunk idx 0..7
      const int xa = l31 & 7;                         // row&7 (wave base %8==0)
      bf16x8 a0 = *(const bf16x8*)(sA + (wr * 64 + l31) * BK + ((ch ^ xa) * 8));
      bf16x8 a1 = *(const bf16x8*)(sA + (wr * 64 + 32 + l31) * BK + ((ch ^ xa) * 8));
      bf16x8 b0 = *(const bf16x8*)(sB + (wc * 64 + l31) * BK + ((ch ^ xa) * 8));
      bf16x8 b1 = *(const bf16x8*)(sB + (wc * 64 + 32 + l31) * BK + ((ch ^ xa) * 8));
      acc[0][0] = __builtin_amdgcn_mfma_f32_32x32x16_bf16(a0, b0, acc[0][0], 0, 0, 0);
      acc[0][1] = __builtin_amdgcn_mfma_f32_32x32x16_bf16(a0, b1, acc[0][1], 0, 0, 0);
      acc[1][0] = __builtin_amdgcn_mfma_f32_32x32x16_bf16(a1, b0, acc[1][0], 0, 0, 0);
      acc[1][1] = __builtin_amdgcn_mfma_f32_32x32x16_bf16(a1, b1, acc[1][1], 0, 0, 0);
    }
    __syncthreads();
  }

  if (EPI == 0) {
    // fused MoE epilogue: gv = sum_{e in top2} w_e*relu(acc + <ll_e,B2[e,f,:]>)
#pragma unroll
    for (int mi = 0; mi < 2; ++mi) {
#pragma unroll
      for (int reg = 0; reg < 16; ++reg) {
        const int row = bm + wr * 64 + mi * 32 + (reg & 3) + 8 * (reg >> 2) + 4 * lk;
        const float* mt = meta + (size_t)row * 16;
        const int e0 = (int)mt[0], e1 = (int)mt[1];
        const float w0 = mt[2], w1 = mt[3];
        const float4 l0 = *(const float4*)(mt + 4);
        const float4 l1 = *(const float4*)(mt + 8);
#pragma unroll
        for (int ni = 0; ni < 2; ++ni) {
          const int f = bn + wc * 64 + ni * 32 + l31;
          const float4 b0 = *(const float4*)(B2 + ((size_t)e0 * Fdim + f) * Rdim);
          const float4 b1 = *(const float4*)(B2 + ((size_t)e1 * Fdim + f) * Rdim);
          const float a = acc[mi][ni][reg];
          const float lora0 = l0.x * b0.x + l0.y * b0.y + l0.z * b0.z + l0.w * b0.w;
          const float lora1 = l1.x * b1.x + l1.y * b1.y + l1.z * b1.z + l1.w * b1.w;
          const float gv = w0 * fmaxf(a + lora0, 0.f) + w1 * fmaxf(a + lora1, 0.f);
          outg[(size_t)row * Fdim + f] = f2bf(gv);
        }
      }
    }
  } else {
    // split-K partial: f32 atomic accumulate (32 lanes x 4B = 128B rows)
#pragma unroll
    for (int mi = 0; mi < 2; ++mi)
#pragma unroll
      for (int ni = 0; ni < 2; ++ni)
#pragma unroll
        for (int reg = 0; reg < 16; ++reg) {
          const int row = bm + wr * 64 + mi * 32 + (reg & 3) + 8 * (reg >> 2) + 4 * lk;
          const int col = bn + wc * 64 + ni * 32 + l31;
          unsafeAtomicAdd(&outf[(size_t)row * Ncols + col], acc[mi][ni][reg]);
        }
  }
}

extern "C" void kernel_launch(void* const* d_in, const int* in_sizes, int n_in,
                              void* d_out, int out_size, void* d_ws, size_t ws_size,
                              hipStream_t stream) {
  const float* x  = (const float*)d_in[0];
  const float* Wg = (const float*)d_in[1];
  const float* bg = (const float*)d_in[2];
  const float* Wi = (const float*)d_in[3];
  const float* Wo = (const float*)d_in[4];
  const float* Aw = (const float*)d_in[5];
  const float* B2 = (const float*)d_in[6];
  float* out = (float*)d_out;

  // workspace layout (bf16 as ushort)
  unsigned short* xb  = (unsigned short*)d_ws;                 // [BSz][Ddim]   8 MB
  unsigned short* wib = xb  + (size_t)BSz  * Ddim;             // [Fdim][Ddim]  8 MB
  unsigned short* wob = wib + (size_t)Fdim * Ddim;             // [Ddim][Fdim]  8 MB
  unsigned short* g   = wob + (size_t)Ddim * Fdim;             // [BSz][Fdim]  32 MB
  float* meta = (float*)(g + (size_t)BSz * Fdim);              // [BSz][16]   256 KB

  const int n4 = BSz * Ddim / 4;   // == Fdim*Ddim/4 == Ddim*Fdim/4
  cvt3_kernel<<<dim3((n4 + 255) / 256, 3), 256, 0, stream>>>(
      x, Wi, Wo, xb, wib, wob, n4);

  router_kernel<<<BSz, 256, 0, stream>>>(x, Wg, bg, Aw, meta);

  // GEMM1: base = x * Wi^T, fused MoE epilogue -> g (bf16); also zeroes out.
  // 128^2 tile, grid 32x32 = 1024 blocks (4/CU), K=1024
  gemm32<0><<<dim3(Fdim / 128, BSz / 128, 1), 256, 0, stream>>>(
      xb, wib, Ddim, Ddim, Fdim, meta, B2, g, nullptr, out);

  // GEMM2: out = g * Wo^T, split-K x4 (slices of 1024), f32 atomics
  // grid 8x32x4 = 1024 blocks (4/CU)
  gemm32<1><<<dim3(Ddim / 128, BSz / 128, 4), 256, 0, stream>>>(
      g, wob, Fdim, Fdim / 4, Ddim, nullptr, nullptr, nullptr, out, nullptr);
}

// Round 12
// 170.783 us; speedup vs baseline: 1.1635x; 1.1635x over previous
//
#include <hip/hip_runtime.h>
#include <stdint.h>

#define BSz 4096   // B*S tokens
#define Ddim 1024
#define Fdim 4096
#define Edim 4
#define Rdim 4

typedef __attribute__((ext_vector_type(8))) short bf16x8;
typedef __attribute__((ext_vector_type(4))) float f32x4;

__device__ __forceinline__ unsigned short f2bf(float f) {
  union { float f; uint32_t u; } c; c.f = f;
  return (unsigned short)((c.u + 0x7fffu + ((c.u >> 16) & 1u)) >> 16);
}

// ---------------- fp32 -> bf16 conversion, 3 tensors in one launch ----------
__global__ __launch_bounds__(256) void cvt3_kernel(const float* __restrict__ x,
                                                   const float* __restrict__ wi,
                                                   const float* __restrict__ wo,
                                                   unsigned short* __restrict__ xb,
                                                   unsigned short* __restrict__ wib,
                                                   unsigned short* __restrict__ wob,
                                                   int n4) {
  int i = blockIdx.x * 256 + threadIdx.x;
  if (i >= n4) return;
  const float* src = (blockIdx.y == 0) ? x : (blockIdx.y == 1) ? wi : wo;
  unsigned short* dst = (blockIdx.y == 0) ? xb : (blockIdx.y == 1) ? wib : wob;
  float4 v = ((const float4*)src)[i];
  ushort4 o;
  o.x = f2bf(v.x); o.y = f2bf(v.y); o.z = f2bf(v.z); o.w = f2bf(v.w);
  ((ushort4*)dst)[i] = o;
}

// ---------------- router: logits -> softmax -> top2 + lora_low ----------------
__global__ __launch_bounds__(256) void router_kernel(const float* __restrict__ x,
                                                     const float* __restrict__ Wg,
                                                     const float* __restrict__ bg,
                                                     const float* __restrict__ Aw,
                                                     float* __restrict__ meta) {
  __shared__ float xs[Ddim];
  __shared__ float dots[Edim + Edim * Rdim];
  const int t = blockIdx.x;
  const float4* xt = (const float4*)(x + (size_t)t * Ddim);
  for (int i = threadIdx.x; i < Ddim / 4; i += 256) ((float4*)xs)[i] = xt[i];
  __syncthreads();
  const int wave = threadIdx.x >> 6, lane = threadIdx.x & 63;
  for (int d = wave * 5; d < wave * 5 + 5; ++d) {
    const float* wrow = (d < Edim) ? (Wg + (size_t)d * Ddim)
                                   : (Aw + (size_t)(d - Edim) * Ddim);
    float s = 0.f;
    for (int i = lane; i < Ddim; i += 64) s += xs[i] * wrow[i];
    for (int off = 32; off; off >>= 1) s += __shfl_down(s, off);
    if (lane == 0) dots[d] = s;
  }
  __syncthreads();
  if (threadIdx.x == 0) {
    float p[Edim];
    float m = -1e30f;
    for (int e = 0; e < Edim; ++e) { p[e] = dots[e] + bg[e]; m = fmaxf(m, p[e]); }
    float sum = 0.f;
    for (int e = 0; e < Edim; ++e) { p[e] = expf(p[e] - m); sum += p[e]; }
    const float inv = 1.f / sum;
    for (int e = 0; e < Edim; ++e) p[e] *= inv;
    int e0 = 0;
    for (int e = 1; e < Edim; ++e) if (p[e] > p[e0]) e0 = e;
    int e1 = (e0 == 0) ? 1 : 0;
    for (int e = 0; e < Edim; ++e) if (e != e0 && p[e] > p[e1]) e1 = e;
    float* mt = meta + (size_t)t * 16;
    mt[0] = (float)e0; mt[1] = (float)e1; mt[2] = p[e0]; mt[3] = p[e1];
    for (int r = 0; r < Rdim; ++r) {
      mt[4 + r] = dots[Edim + e0 * Rdim + r];
      mt[8 + r] = dots[Edim + e1 * Rdim + r];
    }
    mt[12] = 0.f; mt[13] = 0.f; mt[14] = 0.f; mt[15] = 0.f;
  }
}

// ---------------- R6-exact m97-structure NT bf16 GEMM ----------------
// C[M,N] = A[M,K] rows bm.. * B[N,K]^T rows bn.. over K-slice [kbase,+kslice).
// 128x128 tile, BK=64, 4 waves (2x2), single-buffered 32KB LDS, plain
// __syncthreads, 3 blocks/CU. XOR chunk swizzle (chunk ^ row&7) via
// pre-swizzled global source + swizzled ds_read (R6-validated: 0 conflicts,
// best measured GEMM at 73.5 us).
// EPI==0: fused MoE epilogue -> outg bf16 (LDS repack, coalesced stores);
//         also zeroes zbuf (split-K base for GEMM2) before the K-loop.
// EPI==1: f32 atomicAdd into outf (split-K).
template <int EPI>
__global__ __launch_bounds__(256, 3)
void gemm97(const unsigned short* __restrict__ Ag,
            const unsigned short* __restrict__ Bg,
            int K, int kslice, int Ncols,
            const float* __restrict__ meta,
            const float* __restrict__ B2,
            unsigned short* __restrict__ outg,
            float* __restrict__ outf,
            float* __restrict__ zbuf) {
  constexpr int BK = 64;
  __shared__ __align__(16) unsigned short sA[128 * BK];   // 16 KB
  __shared__ __align__(16) unsigned short sB[128 * BK];   // 16 KB

  const int tid = threadIdx.x;
  const int lane = tid & 63;
  const int wave = tid >> 6;            // 0..3
  const int wr = wave >> 1, wc = wave & 1;
  const int l16 = lane & 15, lhi = lane >> 4;

  // XCD-aware bijective swizzle on the xy grid (nwg per z-slice % 8 == 0)
  const int nwg = gridDim.x * gridDim.y;
  const int lin = blockIdx.y * gridDim.x + blockIdx.x;
  const int cpx = nwg >> 3;
  const int swz = (lin & 7) * cpx + (lin >> 3);
  const int bx = swz % gridDim.x, by = swz / gridDim.x;
  const int bm = by * 128, bn = bx * 128;
  const int kbase = blockIdx.z * kslice;
  const int NT = kslice / BK;

  // fused zero of the split-K accumulation target (GEMM1 only): 1024 blocks
  // x 256 thr x 1024 float4-slots/block = 16 MB. Stream order puts this
  // before GEMM2's atomics.
  if (EPI == 0) {
    const float4 z4 = make_float4(0.f, 0.f, 0.f, 0.f);
#pragma unroll
    for (int zz = 0; zz < 4; ++zz)
      ((float4*)zbuf)[(size_t)lin * 1024 + zz * 256 + tid] = z4;
  }

  f32x4 acc[4][4] = {};

  // staging: LDS dest linear (tid*8 elems); global source chunk pre-swizzled
  // by the involution chunk' = chunk ^ (row&7). Round rr: rows tid/8 + rr*32.
  const int srow = tid >> 3;                                  // 0..31
  const int scol = ((tid & 7) ^ (srow & 7)) * 8;              // swizzled col
  const int ldst = tid * 8;
  const int xr = l16 & 7;                                     // read-side XOR

  for (int kt = 0; kt < NT; ++kt) {
    const int kof = kbase + kt * BK;
#pragma unroll
    for (int rr = 0; rr < 4; ++rr)
      __builtin_amdgcn_global_load_lds(
          (const __attribute__((address_space(1))) void*)(Ag + (size_t)(bm + srow + rr * 32) * K + kof + scol),
          (__attribute__((address_space(3))) void*)(sA + ldst + rr * 2048), 16, 0, 0);
#pragma unroll
    for (int rr = 0; rr < 4; ++rr)
      __builtin_amdgcn_global_load_lds(
          (const __attribute__((address_space(1))) void*)(Bg + (size_t)(bn + srow + rr * 32) * K + kof + scol),
          (__attribute__((address_space(3))) void*)(sB + ldst + rr * 2048), 16, 0, 0);
    __syncthreads();
#pragma unroll
    for (int kk = 0; kk < 2; ++kk) {
      bf16x8 af[4], bfv[4];
#pragma unroll
      for (int i = 0; i < 4; ++i) {
        af[i] = *(const bf16x8*)(sA + (wr * 64 + i * 16 + l16) * BK + (((kk * 4 + lhi) ^ xr) * 8));
        bfv[i] = *(const bf16x8*)(sB + (wc * 64 + i * 16 + l16) * BK + (((kk * 4 + lhi) ^ xr) * 8));
      }
#pragma unroll
      for (int i = 0; i < 4; ++i)
#pragma unroll
        for (int j = 0; j < 4; ++j)
          acc[i][j] = __builtin_amdgcn_mfma_f32_16x16x32_bf16(af[i], bfv[j], acc[i][j], 0, 0, 0);
    }
    __syncthreads();
  }

  if (EPI == 0) {
    // fused MoE epilogue: gv = sum_{e in top2} w_e*relu(acc + <ll_e,B2[e,f,:]>)
    // repack through LDS (sA rows 0..63, sB rows 64..127) -> coalesced stores.
#pragma unroll
    for (int mi = 0; mi < 4; ++mi) {
#pragma unroll
      for (int r = 0; r < 4; ++r) {
        const int rowl = wr * 64 + mi * 16 + lhi * 4 + r;     // 0..127
        const int row = bm + rowl;
        const float* mt = meta + (size_t)row * 16;
        const int e0 = (int)mt[0], e1 = (int)mt[1];
        const float w0 = mt[2], w1 = mt[3];
        const float4 l0 = *(const float4*)(mt + 4);
        const float4 l1 = *(const float4*)(mt + 8);
        unsigned short* trow = (rowl < 64 ? sA + rowl * 128 : sB + (rowl - 64) * 128);
#pragma unroll
        for (int ni = 0; ni < 4; ++ni) {
          const int coll = wc * 64 + ni * 16 + l16;
          const int f = bn + coll;
          const float4 b0 = *(const float4*)(B2 + ((size_t)e0 * Fdim + f) * Rdim);
          const float4 b1 = *(const float4*)(B2 + ((size_t)e1 * Fdim + f) * Rdim);
          const float a = acc[mi][ni][r];
          const float lora0 = l0.x * b0.x + l0.y * b0.y + l0.z * b0.z + l0.w * b0.w;
          const float lora1 = l1.x * b1.x + l1.y * b1.y + l1.z * b1.z + l1.w * b1.w;
          const float gv = w0 * fmaxf(a + lora0, 0.f) + w1 * fmaxf(a + lora1, 0.f);
          trow[coll] = f2bf(gv);
        }
      }
    }
    __syncthreads();
    // coalesced copy: 128 rows x 256B; 16 threads/row x 16B; 8 rounds.
#pragma unroll
    for (int rnd = 0; rnd < 8; ++rnd) {
      const int idx = rnd * 256 + tid;          // 0..2047
      const int rowl = idx >> 4;                // 0..127
      const int chk = idx & 15;                 // 16B chunk
      const unsigned short* src = (rowl < 64 ? sA + rowl * 128 : sB + (rowl - 64) * 128) + chk * 8;
      *(bf16x8*)(outg + (size_t)(bm + rowl) * Fdim + bn + chk * 8) = *(const bf16x8*)src;
    }
  } else {
    // split-K partial: f32 atomic accumulate (16 lanes x 4B = 64B sectors)
#pragma unroll
    for (int mi = 0; mi < 4; ++mi)
#pragma unroll
      for (int ni = 0; ni < 4; ++ni)
#pragma unroll
        for (int r = 0; r < 4; ++r) {
          const int row = bm + wr * 64 + mi * 16 + lhi * 4 + r;
          const int col = bn + wc * 64 + ni * 16 + l16;
          unsafeAtomicAdd(&outf[(size_t)row * Ncols + col], acc[mi][ni][r]);
        }
  }
}

extern "C" void kernel_launch(void* const* d_in, const int* in_sizes, int n_in,
                              void* d_out, int out_size, void* d_ws, size_t ws_size,
                              hipStream_t stream) {
  const float* x  = (const float*)d_in[0];
  const float* Wg = (const float*)d_in[1];
  const float* bg = (const float*)d_in[2];
  const float* Wi = (const float*)d_in[3];
  const float* Wo = (const float*)d_in[4];
  const float* Aw = (const float*)d_in[5];
  const float* B2 = (const float*)d_in[6];
  float* out = (float*)d_out;

  // workspace layout (bf16 as ushort)
  unsigned short* xb  = (unsigned short*)d_ws;                 // [BSz][Ddim]   8 MB
  unsigned short* wib = xb  + (size_t)BSz  * Ddim;             // [Fdim][Ddim]  8 MB
  unsigned short* wob = wib + (size_t)Fdim * Ddim;             // [Ddim][Fdim]  8 MB
  unsigned short* g   = wob + (size_t)Ddim * Fdim;             // [BSz][Fdim]  32 MB
  float* meta = (float*)(g + (size_t)BSz * Fdim);              // [BSz][16]   256 KB

  const int n4 = BSz * Ddim / 4;   // == Fdim*Ddim/4 == Ddim*Fdim/4
  cvt3_kernel<<<dim3((n4 + 255) / 256, 3), 256, 0, stream>>>(
      x, Wi, Wo, xb, wib, wob, n4);

  router_kernel<<<BSz, 256, 0, stream>>>(x, Wg, bg, Aw, meta);

  // GEMM1: base = x * Wi^T, fused MoE epilogue -> g (bf16); zeroes out.
  // 128^2 tile, grid 32x32 = 1024 blocks (3/CU), K=1024
  gemm97<0><<<dim3(Fdim / 128, BSz / 128, 1), 256, 0, stream>>>(
      xb, wib, Ddim, Ddim, Fdim, meta, B2, g, nullptr, out);

  // GEMM2: out = g * Wo^T, split-K x2 (slices of 2048 -> 32-tile pipeline),
  // f32 atomics, grid 8x32x2 = 512 blocks (2/CU)
  gemm97<1><<<dim3(Ddim / 128, BSz / 128, 2), 256, 0, stream>>>(
      g, wob, Fdim, Fdim / 2, Ddim, nullptr, nullptr, nullptr, out, nullptr);
}

// Round 13
// 168.507 us; speedup vs baseline: 1.1792x; 1.0135x over previous
//
#include <hip/hip_runtime.h>
#include <stdint.h>

#define BSz 4096   // B*S tokens
#define Ddim 1024
#define Fdim 4096
#define Edim 4
#define Rdim 4

typedef __attribute__((ext_vector_type(8))) short bf16x8;
typedef __attribute__((ext_vector_type(4))) float f32x4;

__device__ __forceinline__ unsigned short f2bf(float f) {
  union { float f; uint32_t u; } c; c.f = f;
  return (unsigned short)((c.u + 0x7fffu + ((c.u >> 16) & 1u)) >> 16);
}

// ---------------- fp32 -> bf16 conversion, Wi + Wo in one launch ----------
__global__ __launch_bounds__(256) void cvt2_kernel(const float* __restrict__ wi,
                                                   const float* __restrict__ wo,
                                                   unsigned short* __restrict__ wib,
                                                   unsigned short* __restrict__ wob,
                                                   int n4) {
  int i = blockIdx.x * 256 + threadIdx.x;
  if (i >= n4) return;
  const float* src = (blockIdx.y == 0) ? wi : wo;
  unsigned short* dst = (blockIdx.y == 0) ? wib : wob;
  float4 v = ((const float4*)src)[i];
  ushort4 o;
  o.x = f2bf(v.x); o.y = f2bf(v.y); o.z = f2bf(v.z); o.w = f2bf(v.w);
  ((ushort4*)dst)[i] = o;
}

// ------- router + cvt(x): one pass over x -> xb (bf16) + meta -------------
// meta[t][0..15]: e0, e1, w0, w1, ll0[0..3], ll1[0..3], pad
__global__ __launch_bounds__(256) void router_cvtx(const float* __restrict__ x,
                                                   const float* __restrict__ Wg,
                                                   const float* __restrict__ bg,
                                                   const float* __restrict__ Aw,
                                                   unsigned short* __restrict__ xb,
                                                   float* __restrict__ meta) {
  __shared__ float xs[Ddim];
  __shared__ float dots[Edim + Edim * Rdim];
  const int t = blockIdx.x;
  const float4* xt = (const float4*)(x + (size_t)t * Ddim);
  // load row, stash in LDS, and write the bf16 copy (fused cvt)
  {
    const int i = threadIdx.x;                       // 256 thr x float4 = 1024
    float4 v = xt[i];
    ((float4*)xs)[i] = v;
    ushort4 o;
    o.x = f2bf(v.x); o.y = f2bf(v.y); o.z = f2bf(v.z); o.w = f2bf(v.w);
    ((ushort4*)(xb + (size_t)t * Ddim))[i] = o;
  }
  __syncthreads();
  const int wave = threadIdx.x >> 6, lane = threadIdx.x & 63;
  for (int d = wave * 5; d < wave * 5 + 5; ++d) {
    const float* wrow = (d < Edim) ? (Wg + (size_t)d * Ddim)
                                   : (Aw + (size_t)(d - Edim) * Ddim);
    float s = 0.f;
    for (int i = lane; i < Ddim; i += 64) s += xs[i] * wrow[i];
    for (int off = 32; off; off >>= 1) s += __shfl_down(s, off);
    if (lane == 0) dots[d] = s;
  }
  __syncthreads();
  if (threadIdx.x == 0) {
    float p[Edim];
    float m = -1e30f;
    for (int e = 0; e < Edim; ++e) { p[e] = dots[e] + bg[e]; m = fmaxf(m, p[e]); }
    float sum = 0.f;
    for (int e = 0; e < Edim; ++e) { p[e] = expf(p[e] - m); sum += p[e]; }
    const float inv = 1.f / sum;
    for (int e = 0; e < Edim; ++e) p[e] *= inv;
    int e0 = 0;
    for (int e = 1; e < Edim; ++e) if (p[e] > p[e0]) e0 = e;
    int e1 = (e0 == 0) ? 1 : 0;
    for (int e = 0; e < Edim; ++e) if (e != e0 && p[e] > p[e1]) e1 = e;
    float* mt = meta + (size_t)t * 16;
    mt[0] = (float)e0; mt[1] = (float)e1; mt[2] = p[e0]; mt[3] = p[e1];
    for (int r = 0; r < Rdim; ++r) {
      mt[4 + r] = dots[Edim + e0 * Rdim + r];
      mt[8 + r] = dots[Edim + e1 * Rdim + r];
    }
    mt[12] = 0.f; mt[13] = 0.f; mt[14] = 0.f; mt[15] = 0.f;
  }
}

// ---------------- R12-structure NT bf16 GEMM (4 blocks/CU) ----------------
// C[M,N] = A[M,K] rows bm.. * B[N,K]^T rows bn.. over K-slice [kbase,+kslice).
// 128x128 tile, BK=64, 4 waves (2x2), single-buffered 32KB LDS, plain
// __syncthreads. XOR chunk swizzle (chunk ^ row&7) via pre-swizzled global
// source + swizzled ds_read (R6/R12-validated). 4 blocks/CU (clean A/B vs
// R12's 3 — more cross-block DMA overlap, the one lever that has worked).
// EPI==0: fused MoE epilogue -> outg bf16 (LDS repack, coalesced stores);
//         also zeroes zbuf (split-K base for GEMM2) before the K-loop.
// EPI==1: f32 atomicAdd into outf (split-K).
template <int EPI>
__global__ __launch_bounds__(256, 4)
void gemm97(const unsigned short* __restrict__ Ag,
            const unsigned short* __restrict__ Bg,
            int K, int kslice, int Ncols,
            const float* __restrict__ meta,
            const float* __restrict__ B2,
            unsigned short* __restrict__ outg,
            float* __restrict__ outf,
            float* __restrict__ zbuf) {
  constexpr int BK = 64;
  __shared__ __align__(16) unsigned short sA[128 * BK];   // 16 KB
  __shared__ __align__(16) unsigned short sB[128 * BK];   // 16 KB

  const int tid = threadIdx.x;
  const int lane = tid & 63;
  const int wave = tid >> 6;            // 0..3
  const int wr = wave >> 1, wc = wave & 1;
  const int l16 = lane & 15, lhi = lane >> 4;

  // XCD-aware bijective swizzle on the xy grid (nwg per z-slice % 8 == 0)
  const int nwg = gridDim.x * gridDim.y;
  const int lin = blockIdx.y * gridDim.x + blockIdx.x;
  const int cpx = nwg >> 3;
  const int swz = (lin & 7) * cpx + (lin >> 3);
  const int bx = swz % gridDim.x, by = swz / gridDim.x;
  const int bm = by * 128, bn = bx * 128;
  const int kbase = blockIdx.z * kslice;
  const int NT = kslice / BK;

  // fused zero of the split-K accumulation target (GEMM1 only): 1024 blocks
  // x 256 thr x 4 float4 = 16 MB. Stream order puts this before GEMM2.
  if (EPI == 0) {
    const float4 z4 = make_float4(0.f, 0.f, 0.f, 0.f);
#pragma unroll
    for (int zz = 0; zz < 4; ++zz)
      ((float4*)zbuf)[(size_t)lin * 1024 + zz * 256 + tid] = z4;
  }

  f32x4 acc[4][4] = {};

  // staging: LDS dest linear (tid*8 elems); global source chunk pre-swizzled
  // by the involution chunk' = chunk ^ (row&7). Round rr: rows tid/8 + rr*32.
  const int srow = tid >> 3;                                  // 0..31
  const int scol = ((tid & 7) ^ (srow & 7)) * 8;              // swizzled col
  const int ldst = tid * 8;
  const int xr = l16 & 7;                                     // read-side XOR

  for (int kt = 0; kt < NT; ++kt) {
    const int kof = kbase + kt * BK;
#pragma unroll
    for (int rr = 0; rr < 4; ++rr)
      __builtin_amdgcn_global_load_lds(
          (const __attribute__((address_space(1))) void*)(Ag + (size_t)(bm + srow + rr * 32) * K + kof + scol),
          (__attribute__((address_space(3))) void*)(sA + ldst + rr * 2048), 16, 0, 0);
#pragma unroll
    for (int rr = 0; rr < 4; ++rr)
      __builtin_amdgcn_global_load_lds(
          (const __attribute__((address_space(1))) void*)(Bg + (size_t)(bn + srow + rr * 32) * K + kof + scol),
          (__attribute__((address_space(3))) void*)(sB + ldst + rr * 2048), 16, 0, 0);
    __syncthreads();
#pragma unroll
    for (int kk = 0; kk < 2; ++kk) {
      bf16x8 af[4], bfv[4];
#pragma unroll
      for (int i = 0; i < 4; ++i) {
        af[i] = *(const bf16x8*)(sA + (wr * 64 + i * 16 + l16) * BK + (((kk * 4 + lhi) ^ xr) * 8));
        bfv[i] = *(const bf16x8*)(sB + (wc * 64 + i * 16 + l16) * BK + (((kk * 4 + lhi) ^ xr) * 8));
      }
#pragma unroll
      for (int i = 0; i < 4; ++i)
#pragma unroll
        for (int j = 0; j < 4; ++j)
          acc[i][j] = __builtin_amdgcn_mfma_f32_16x16x32_bf16(af[i], bfv[j], acc[i][j], 0, 0, 0);
    }
    __syncthreads();
  }

  if (EPI == 0) {
    // fused MoE epilogue: gv = sum_{e in top2} w_e*relu(acc + <ll_e,B2[e,f,:]>)
    // repack through LDS (sA rows 0..63, sB rows 64..127) -> coalesced stores.
#pragma unroll
    for (int mi = 0; mi < 4; ++mi) {
#pragma unroll
      for (int r = 0; r < 4; ++r) {
        const int rowl = wr * 64 + mi * 16 + lhi * 4 + r;     // 0..127
        const int row = bm + rowl;
        const float* mt = meta + (size_t)row * 16;
        const int e0 = (int)mt[0], e1 = (int)mt[1];
        const float w0 = mt[2], w1 = mt[3];
        const float4 l0 = *(const float4*)(mt + 4);
        const float4 l1 = *(const float4*)(mt + 8);
        unsigned short* trow = (rowl < 64 ? sA + rowl * 128 : sB + (rowl - 64) * 128);
#pragma unroll
        for (int ni = 0; ni < 4; ++ni) {
          const int coll = wc * 64 + ni * 16 + l16;
          const int f = bn + coll;
          const float4 b0 = *(const float4*)(B2 + ((size_t)e0 * Fdim + f) * Rdim);
          const float4 b1 = *(const float4*)(B2 + ((size_t)e1 * Fdim + f) * Rdim);
          const float a = acc[mi][ni][r];
          const float lora0 = l0.x * b0.x + l0.y * b0.y + l0.z * b0.z + l0.w * b0.w;
          const float lora1 = l1.x * b1.x + l1.y * b1.y + l1.z * b1.z + l1.w * b1.w;
          const float gv = w0 * fmaxf(a + lora0, 0.f) + w1 * fmaxf(a + lora1, 0.f);
          trow[coll] = f2bf(gv);
        }
      }
    }
    __syncthreads();
    // coalesced copy: 128 rows x 256B; 16 threads/row x 16B; 8 rounds.
#pragma unroll
    for (int rnd = 0; rnd < 8; ++rnd) {
      const int idx = rnd * 256 + tid;          // 0..2047
      const int rowl = idx >> 4;                // 0..127
      const int chk = idx & 15;                 // 16B chunk
      const unsigned short* src = (rowl < 64 ? sA + rowl * 128 : sB + (rowl - 64) * 128) + chk * 8;
      *(bf16x8*)(outg + (size_t)(bm + rowl) * Fdim + bn + chk * 8) = *(const bf16x8*)src;
    }
  } else {
    // split-K partial: f32 atomic accumulate (16 lanes x 4B = 64B sectors)
#pragma unroll
    for (int mi = 0; mi < 4; ++mi)
#pragma unroll
      for (int ni = 0; ni < 4; ++ni)
#pragma unroll
        for (int r = 0; r < 4; ++r) {
          const int row = bm + wr * 64 + mi * 16 + lhi * 4 + r;
          const int col = bn + wc * 64 + ni * 16 + l16;
          unsafeAtomicAdd(&outf[(size_t)row * Ncols + col], acc[mi][ni][r]);
        }
  }
}

extern "C" void kernel_launch(void* const* d_in, const int* in_sizes, int n_in,
                              void* d_out, int out_size, void* d_ws, size_t ws_size,
                              hipStream_t stream) {
  const float* x  = (const float*)d_in[0];
  const float* Wg = (const float*)d_in[1];
  const float* bg = (const float*)d_in[2];
  const float* Wi = (const float*)d_in[3];
  const float* Wo = (const float*)d_in[4];
  const float* Aw = (const float*)d_in[5];
  const float* B2 = (const float*)d_in[6];
  float* out = (float*)d_out;

  // workspace layout (bf16 as ushort)
  unsigned short* xb  = (unsigned short*)d_ws;                 // [BSz][Ddim]   8 MB
  unsigned short* wib = xb  + (size_t)BSz  * Ddim;             // [Fdim][Ddim]  8 MB
  unsigned short* wob = wib + (size_t)Fdim * Ddim;             // [Ddim][Fdim]  8 MB
  unsigned short* g   = wob + (size_t)Ddim * Fdim;             // [BSz][Fdim]  32 MB
  float* meta = (float*)(g + (size_t)BSz * Fdim);              // [BSz][16]   256 KB

  const int n4 = Fdim * Ddim / 4;
  cvt2_kernel<<<dim3((n4 + 255) / 256, 2), 256, 0, stream>>>(
      Wi, Wo, wib, wob, n4);

  // router + cvt(x) fused: one pass over x
  router_cvtx<<<BSz, 256, 0, stream>>>(x, Wg, bg, Aw, xb, meta);

  // GEMM1: base = x * Wi^T, fused MoE epilogue -> g (bf16); zeroes out.
  // 128^2 tile, grid 32x32 = 1024 blocks (4/CU), K=1024
  gemm97<0><<<dim3(Fdim / 128, BSz / 128, 1), 256, 0, stream>>>(
      xb, wib, Ddim, Ddim, Fdim, meta, B2, g, nullptr, out);

  // GEMM2: out = g * Wo^T, split-K x2 (slices of 2048 -> 32-tile pipeline),
  // f32 atomics, grid 8x32x2 = 512 blocks (2/CU)
  gemm97<1><<<dim3(Ddim / 128, BSz / 128, 2), 256, 0, stream>>>(
      g, wob, Fdim, Fdim / 2, Ddim, nullptr, nullptr, nullptr, out, nullptr);
}